// Round 9
// baseline (127.041 us; speedup 1.0000x reference)
//
#include <hip/hip_runtime.h>
#include <hip/hip_fp16.h>
#include <math.h>

#define NH 16
#define NWL 16

typedef _Float16 half8 __attribute__((ext_vector_type(8)));
typedef _Float16 half4 __attribute__((ext_vector_type(4)));
typedef float f32x4 __attribute__((ext_vector_type(4)));

// ---------------------------------------------------------------------------
// cast x (fp32 -> f16), 8 elems/thread
// ---------------------------------------------------------------------------
__global__ __launch_bounds__(256)
void cast_x_k(const float* __restrict__ X, _Float16* __restrict__ Xh)
{
    const int i = (blockIdx.x * 256 + threadIdx.x) * 8;
    float4 v0 = *(const float4*)&X[i];
    float4 v1 = *(const float4*)&X[i + 4];
    half8 o;
    o[0] = (_Float16)v0.x; o[1] = (_Float16)v0.y; o[2] = (_Float16)v0.z; o[3] = (_Float16)v0.w;
    o[4] = (_Float16)v1.x; o[5] = (_Float16)v1.y; o[6] = (_Float16)v1.z; o[7] = (_Float16)v1.w;
    *(half8*)&Xh[i] = o;
}

// ---------------------------------------------------------------------------
// cast + transpose W[e][f] -> WT[f][e] f16, 64x64 tiles, z picks which W
// ---------------------------------------------------------------------------
__global__ __launch_bounds__(256)
void castT_w(const float* __restrict__ W0, const float* __restrict__ W1,
             const float* __restrict__ W2, const float* __restrict__ W3,
             _Float16* __restrict__ WT)
{
    const float* W = W0;
    if (blockIdx.z == 1) W = W1;
    if (blockIdx.z == 2) W = W2;
    if (blockIdx.z == 3) W = W3;
    _Float16* out = WT + ((size_t)blockIdx.z << 20);

    __shared__ float Ts[64][65];
    const int t = threadIdx.x;
    const int ebase = blockIdx.y * 64;
    const int fbase = blockIdx.x * 64;

    {
        const int r0 = (t >> 4) * 4;
        const int c0 = (t & 15) * 4;
#pragma unroll
        for (int r = 0; r < 4; ++r) {
            float4 v = *(const float4*)&W[(size_t)(ebase + r0 + r) * 1024 + fbase + c0];
            Ts[r0 + r][c0 + 0] = v.x;
            Ts[r0 + r][c0 + 1] = v.y;
            Ts[r0 + r][c0 + 2] = v.z;
            Ts[r0 + r][c0 + 3] = v.w;
        }
    }
    __syncthreads();

    const int f = t >> 2;
    const int eseg = (t & 3) * 16;
    half8 lo, hi;
#pragma unroll
    for (int j = 0; j < 8; ++j) lo[j] = (_Float16)Ts[eseg + j][f];
#pragma unroll
    for (int j = 0; j < 8; ++j) hi[j] = (_Float16)Ts[eseg + 8 + j][f];
    *(half8*)&out[(size_t)(fbase + f) * 1024 + ebase + eseg]     = lo;
    *(half8*)&out[(size_t)(fbase + f) * 1024 + ebase + eseg + 8] = hi;
}

// ---------------------------------------------------------------------------
// MFMA GEMM (f16): C[s][f] = sum_e A[s][e]*W[e][f] + bias[f]
// 64x64 tile, BK=32, 4 waves (2x2), 16x16x32_f16 frags, double-buffered LDS.
// MODE 0: fp32 out[s][f]
// MODE 1: f16 head-split: z=0,1 -> O[h][s][d]; z=2 -> transposed O[h][d][s]
// ---------------------------------------------------------------------------
template<int MODE>
__global__ __launch_bounds__(256)
void gemm_mfma(const _Float16* __restrict__ A,
               const _Float16* __restrict__ BtBase,
               const float* __restrict__ B0, const float* __restrict__ B1,
               const float* __restrict__ B2,
               void* __restrict__ O0p, void* __restrict__ O1p, void* __restrict__ O2p)
{
    const int z = blockIdx.z;
    const _Float16* Bt = BtBase + ((size_t)z << 20);
    const float* bias = B0; void* Op = O0p;
    if (z == 1) { bias = B1; Op = O1p; }
    if (z == 2) { bias = B2; Op = O2p; }

    __shared__ _Float16 As[2][64][40];
    __shared__ _Float16 Bs[2][64][40];

    const int t = threadIdx.x;
    const int lane = t & 63;
    const int w = t >> 6;
    const int w_r = w >> 1;
    const int w_c = w & 1;
    const int sbase = blockIdx.y * 64;
    const int fbase = blockIdx.x * 64;

    const int srow = t >> 2;
    const int skseg = (t & 3) * 8;

    f32x4 acc[2][2];
#pragma unroll
    for (int m = 0; m < 2; ++m)
#pragma unroll
        for (int n = 0; n < 2; ++n) acc[m][n] = (f32x4){0.f, 0.f, 0.f, 0.f};

    const int lr = lane & 15;
    const int lk = (lane >> 4) * 8;

    {
        *(half8*)&As[0][srow][skseg] = *(const half8*)&A [(size_t)(sbase + srow) * 1024 + skseg];
        *(half8*)&Bs[0][srow][skseg] = *(const half8*)&Bt[(size_t)(fbase + srow) * 1024 + skseg];
    }
    __syncthreads();

    for (int tile = 0; tile < 32; ++tile) {
        const int cur = tile & 1;
        if (tile < 31) {
            const int kb = (tile + 1) * 32;
            half8 av = *(const half8*)&A [(size_t)(sbase + srow) * 1024 + kb + skseg];
            half8 bv = *(const half8*)&Bt[(size_t)(fbase + srow) * 1024 + kb + skseg];
            *(half8*)&As[cur ^ 1][srow][skseg] = av;
            *(half8*)&Bs[cur ^ 1][srow][skseg] = bv;
        }
        half8 a0 = *(const half8*)&As[cur][w_r * 32 + 0  + lr][lk];
        half8 a1 = *(const half8*)&As[cur][w_r * 32 + 16 + lr][lk];
        half8 b0 = *(const half8*)&Bs[cur][w_c * 32 + 0  + lr][lk];
        half8 b1 = *(const half8*)&Bs[cur][w_c * 32 + 16 + lr][lk];
        acc[0][0] = __builtin_amdgcn_mfma_f32_16x16x32_f16(a0, b0, acc[0][0], 0, 0, 0);
        acc[0][1] = __builtin_amdgcn_mfma_f32_16x16x32_f16(a0, b1, acc[0][1], 0, 0, 0);
        acc[1][0] = __builtin_amdgcn_mfma_f32_16x16x32_f16(a1, b0, acc[1][0], 0, 0, 0);
        acc[1][1] = __builtin_amdgcn_mfma_f32_16x16x32_f16(a1, b1, acc[1][1], 0, 0, 0);
        __syncthreads();
    }

#pragma unroll
    for (int m = 0; m < 2; ++m) {
        const int row0 = sbase + w_r * 32 + m * 16 + (lane >> 4) * 4;
#pragma unroll
        for (int n = 0; n < 2; ++n) {
            const int col = fbase + w_c * 32 + n * 16 + (lane & 15);
            const float bval = bias[col];
            if (MODE == 0) {
                float* O = (float*)Op;
#pragma unroll
                for (int r = 0; r < 4; ++r)
                    O[(size_t)(row0 + r) * 1024 + col] = acc[m][n][r] + bval;
            } else {
                _Float16* O = (_Float16*)Op;
                const int hh = col >> 6;
                const int d = col & 63;
                if (z == 2) {   // V transposed: O[h][d][s]
                    half4 o;
#pragma unroll
                    for (int r = 0; r < 4; ++r) o[r] = (_Float16)(acc[m][n][r] + bval);
                    *(half4*)&O[((size_t)hh << 16) + (size_t)d * 1024 + row0] = o;
                } else {        // Q/K: O[h][s][d]
#pragma unroll
                    for (int r = 0; r < 4; ++r)
                        O[((size_t)hh << 16) + (size_t)(row0 + r) * 64 + d] =
                            (_Float16)(acc[m][n][r] + bval);
                }
            }
        }
    }
}

// ---------------------------------------------------------------------------
// Fused attention, SINGLE-PASS moment-PV form.
//   P(s) = 2^{abar*s} * (c0 + c1 s + c2 s^2 + c3 s^3)   (deg-3, |γs|<=0.17)
//   O[q] = sum_m c_m(q) * PV_m,  PV_m = sum_k s^m 2^{abar s} V[k]  (den-free!)
// One pass over k: QK^T -> powers {e, se, s2e, s3e} (4-mul chain) -> f16 ->
// 4 moment-PV MFMA accumulations + scalar moments M_m (for den).
// Epilogue: den_i = sum gt[i][m] M_m -> wgt -> c_m -> combine 4 accumulators.
// vs 2-pass: half the K reads / QK^T / exps; 40 MFMA per 64k chunk gives the
// scheduler work to hide L2-load latency (R8: latency-bound, VALU 33% idle).
// Block: 256 thr = 4 waves; (head, 16 q); wave owns k-quarter. Grid 1024.
// macc = 4m x 4d f32x4 = 64 acc regs; total ~116 < 128 cap (256,4) -> no spill.
// ---------------------------------------------------------------------------
__global__ __launch_bounds__(256, 4)
void attn_k(const _Float16* __restrict__ Qg, const _Float16* __restrict__ Kg,
            const _Float16* __restrict__ Vg, const float* __restrict__ pm,
            const float* __restrict__ iwp, _Float16* __restrict__ comb)
{
    const int wg  = blockIdx.x;
    const int xcd = wg & 7;
    const int idx = wg >> 3;            // 0..127
    const int h   = xcd * 2 + (idx >> 6);
    const int qt  = idx & 63;           // 16-row q tile

    const int t = threadIdx.x;
    const int lane = t & 63;
    const int w = t >> 6;               // wave id = k-quarter
    const int lr = lane & 15;
    const int lg = lane >> 4;

    __shared__ union {
        _Float16 Ps[4][4][16][68];                       // [wave][moment][q][k64]
        struct { float Mom[4][16][4]; float Red[4][16][68]; } E;
    } U;
    __shared__ float sa[16], siw[16];
    __shared__ float gt[16][4];          // gamma_i^m / m!
    __shared__ float Ctab[16][4];        // c_m per q row

    if (t < 16) {
        float m = cosf(pm[t * NH + h]);
        sa[t] = m * m * 0.125f * 1.44269504f;   // a_i (log2 scale, per raw dot)
        siw[t] = iwp[t];
    }
    __syncthreads();

    float amin = sa[0], amax = sa[0];
#pragma unroll
    for (int i = 1; i < NWL; ++i) {
        amin = fminf(amin, sa[i]);
        amax = fmaxf(amax, sa[i]);
    }
    const float abar = 0.5f * (amin + amax);

    if (t < 16) {
        float g = (sa[t] - abar) * 0.69314718f;  // natural-log residual
        gt[t][0] = 1.f;
        gt[t][1] = g;
        gt[t][2] = g * g * 0.5f;
        gt[t][3] = g * g * g * (1.f / 6.f);
    }
    // gt is read only after the post-k-loop barrier -> ordering safe

    // Q fragments (B-operand): col = q-local = lr, k-seg = lg*8
    const _Float16* Qrow = Qg + ((size_t)h << 16) + (size_t)(qt * 16 + lr) * 64;
    half8 q0 = *(const half8*)&Qrow[lg * 8];
    half8 q1 = *(const half8*)&Qrow[32 + lg * 8];

    const _Float16* Kq = Kg + ((size_t)h << 16) + (size_t)(w * 256) * 64;  // k-quarter
    const _Float16* Vh = Vg + ((size_t)h << 16);                           // V^T [d][s]

    float M0 = 0.f, M1 = 0.f, M2 = 0.f, M3 = 0.f;
    f32x4 macc[4][4];
#pragma unroll
    for (int m = 0; m < 4; ++m)
#pragma unroll
        for (int n = 0; n < 4; ++n) macc[m][n] = (f32x4){0.f, 0.f, 0.f, 0.f};

    for (int ch = 0; ch < 4; ++ch) {
        // ---- QK^T + moment powers for this 64k chunk ----
#pragma unroll
        for (int kf = 0; kf < 4; ++kf) {
            const _Float16* Kr = Kq + (size_t)(ch * 64 + kf * 16 + lr) * 64;
            half8 a0 = *(const half8*)&Kr[lg * 8];
            half8 a1 = *(const half8*)&Kr[32 + lg * 8];
            f32x4 s2 = (f32x4){0.f, 0.f, 0.f, 0.f};
            s2 = __builtin_amdgcn_mfma_f32_16x16x32_f16(a0, q0, s2, 0, 0, 0);
            s2 = __builtin_amdgcn_mfma_f32_16x16x32_f16(a1, q1, s2, 0, 0, 0);
            half4 p0, p1, p2, p3;
#pragma unroll
            for (int r = 0; r < 4; ++r) {
                const float sv = s2[r];
                const float e   = exp2f(abar * sv);
                const float es  = e * sv;
                const float tt  = sv * sv;
                const float et  = e * tt;
                const float est = es * tt;
                M0 += e; M1 += es; M2 += et; M3 += est;
                p0[r] = (_Float16)e;
                p1[r] = (_Float16)es;
                p2[r] = (_Float16)et;
                p3[r] = (_Float16)est;
            }
            const int kl = kf * 16 + lg * 4;   // P_m[q=lr][k-local], wave-private
            *(half4*)&U.Ps[w][0][lr][kl] = p0;
            *(half4*)&U.Ps[w][1][lr][kl] = p1;
            *(half4*)&U.Ps[w][2][lr][kl] = p2;
            *(half4*)&U.Ps[w][3][lr][kl] = p3;
        }
        // ---- 4 moment-PV accumulations (same-wave LDS dep, lgkm waits) ----
        const int kcol = w * 256 + ch * 64;
#pragma unroll
        for (int m = 0; m < 4; ++m) {
            half8 pa0 = *(const half8*)&U.Ps[w][m][lr][lg * 8];
            half8 pa1 = *(const half8*)&U.Ps[w][m][lr][32 + lg * 8];
#pragma unroll
            for (int n = 0; n < 4; ++n) {
                const _Float16* Vr = Vh + (size_t)(n * 16 + lr) * 1024 + kcol;
                half8 vb0 = *(const half8*)&Vr[lg * 8];
                half8 vb1 = *(const half8*)&Vr[32 + lg * 8];
                macc[m][n] = __builtin_amdgcn_mfma_f32_16x16x32_f16(pa0, vb0, macc[m][n], 0, 0, 0);
                macc[m][n] = __builtin_amdgcn_mfma_f32_16x16x32_f16(pa1, vb1, macc[m][n], 0, 0, 0);
            }
        }
    }
    __syncthreads();   // all waves done with Ps; union region switches to E

    // ---- scalar moment reduce: lanes with same lr sum over lg (k bits) ----
#pragma unroll
    for (int off = 16; off < 64; off <<= 1) {
        M0 += __shfl_xor(M0, off);
        M1 += __shfl_xor(M1, off);
        M2 += __shfl_xor(M2, off);
        M3 += __shfl_xor(M3, off);
    }
    if (lg == 0) {
        U.E.Mom[w][lr][0] = M0;
        U.E.Mom[w][lr][1] = M1;
        U.E.Mom[w][lr][2] = M2;
        U.E.Mom[w][lr][3] = M3;
    }
    __syncthreads();

    float Mf[4];
#pragma unroll
    for (int m = 0; m < 4; ++m)
        Mf[m] = U.E.Mom[0][lr][m] + U.E.Mom[1][lr][m] + U.E.Mom[2][lr][m] + U.E.Mom[3][lr][m];

    // den_i = sum_m gt[i][m] Mf[m]; wgt = iw/(16 den); c_m = sum_i wgt gt[i][m]
    float c0 = 0.f, c1 = 0.f, c2 = 0.f, c3 = 0.f;
#pragma unroll
    for (int i = 0; i < NWL; ++i) {
        float den = gt[i][0] * Mf[0];
        den = fmaf(gt[i][1], Mf[1], den);
        den = fmaf(gt[i][2], Mf[2], den);
        den = fmaf(gt[i][3], Mf[3], den);
        const float wgt = siw[i] / (den * 16.0f);
        c0 = fmaf(wgt, gt[i][0], c0);
        c1 = fmaf(wgt, gt[i][1], c1);
        c2 = fmaf(wgt, gt[i][2], c2);
        c3 = fmaf(wgt, gt[i][3], c3);
    }
    if (t < 16) {   // t<16 <=> (w==0, lg==0, lr==t): canonical writer per q row
        Ctab[t][0] = c0; Ctab[t][1] = c1; Ctab[t][2] = c2; Ctab[t][3] = c3;
    }
    __syncthreads();

    // ---- combine 4 moment accumulators; write per-wave O partials ----
    // macc C-layout: row q = lg*4 + r, col d = n*16 + lr
#pragma unroll
    for (int n = 0; n < 4; ++n) {
#pragma unroll
        for (int r = 0; r < 4; ++r) {
            const int q = lg * 4 + r;
            float o = Ctab[q][0] * macc[0][n][r];
            o = fmaf(Ctab[q][1], macc[1][n][r], o);
            o = fmaf(Ctab[q][2], macc[2][n][r], o);
            o = fmaf(Ctab[q][3], macc[3][n][r], o);
            U.E.Red[w][q][n * 16 + lr] = o;
        }
    }
    __syncthreads();

    // ---- final cross-wave reduce: thread t -> q = t>>4, d0 = (t&15)*4 ----
    {
        const int q = t >> 4;
        const int d0 = (t & 15) * 4;
        f32x4 s0 = *(const f32x4*)&U.E.Red[0][q][d0];
        f32x4 s1 = *(const f32x4*)&U.E.Red[1][q][d0];
        f32x4 s2v = *(const f32x4*)&U.E.Red[2][q][d0];
        f32x4 s3 = *(const f32x4*)&U.E.Red[3][q][d0];
        f32x4 sum = s0 + s1 + s2v + s3;
        half4 o;
#pragma unroll
        for (int r = 0; r < 4; ++r) o[r] = (_Float16)sum[r];
        *(half4*)&comb[(size_t)(qt * 16 + q) * 1024 + h * 64 + d0] = o;
    }
}

// ---------------------------------------------------------------------------
extern "C" void kernel_launch(void* const* d_in, const int* in_sizes, int n_in,
                              void* d_out, int out_size, void* d_ws, size_t ws_size,
                              hipStream_t stream)
{
    const float* x  = (const float*)d_in[0];
    const float* Wq = (const float*)d_in[1];
    const float* bq = (const float*)d_in[2];
    const float* Wk = (const float*)d_in[3];
    const float* bk = (const float*)d_in[4];
    const float* Wv = (const float*)d_in[5];
    const float* bv = (const float*)d_in[6];
    const float* Wo = (const float*)d_in[7];
    const float* bo = (const float*)d_in[8];
    const float* pm = (const float*)d_in[9];
    const float* iw = (const float*)d_in[10];
    float* out = (float*)d_out;

    // ws (f16 elems): Xh 1M (reused as comb) | WT 4M | Q 1M | K 1M | Vt 1M = 16 MB
    _Float16* Xh = (_Float16*)d_ws;
    _Float16* WT = Xh + (1u << 20);
    _Float16* Qh = WT + (4u << 20);
    _Float16* Kh = Qh + (1u << 20);
    _Float16* Vt = Kh + (1u << 20);
    _Float16* comb = Xh;   // Xh dead after QKV GEMM

    dim3 blk(256);
    cast_x_k<<<dim3(512), blk, 0, stream>>>(x, Xh);
    castT_w<<<dim3(16, 16, 4), blk, 0, stream>>>(Wq, Wk, Wv, Wo, WT);
    gemm_mfma<1><<<dim3(16, 16, 3), blk, 0, stream>>>(Xh, WT, bq, bk, bv, Qh, Kh, Vt);
    attn_k<<<dim3(1024), blk, 0, stream>>>(Qh, Kh, Vt, pm, iw, comb);
    gemm_mfma<0><<<dim3(16, 16, 1), blk, 0, stream>>>(
        comb, WT + (3u << 20), bo, bo, bo, out, out, out);
}

// Round 10
// 117.106 us; speedup vs baseline: 1.0848x; 1.0848x over previous
//
#include <hip/hip_runtime.h>
#include <hip/hip_fp16.h>
#include <math.h>

#define NH 16
#define NWL 16

typedef _Float16 half8 __attribute__((ext_vector_type(8)));
typedef _Float16 half4 __attribute__((ext_vector_type(4)));
typedef float f32x4 __attribute__((ext_vector_type(4)));

// ---------------------------------------------------------------------------
// cast x (fp32 -> f16), 8 elems/thread
// ---------------------------------------------------------------------------
__global__ __launch_bounds__(256)
void cast_x_k(const float* __restrict__ X, _Float16* __restrict__ Xh)
{
    const int i = (blockIdx.x * 256 + threadIdx.x) * 8;
    float4 v0 = *(const float4*)&X[i];
    float4 v1 = *(const float4*)&X[i + 4];
    half8 o;
    o[0] = (_Float16)v0.x; o[1] = (_Float16)v0.y; o[2] = (_Float16)v0.z; o[3] = (_Float16)v0.w;
    o[4] = (_Float16)v1.x; o[5] = (_Float16)v1.y; o[6] = (_Float16)v1.z; o[7] = (_Float16)v1.w;
    *(half8*)&Xh[i] = o;
}

// ---------------------------------------------------------------------------
// cast + transpose W[e][f] -> WT[f][e] f16, 64x64 tiles, z picks which W
// ---------------------------------------------------------------------------
__global__ __launch_bounds__(256)
void castT_w(const float* __restrict__ W0, const float* __restrict__ W1,
             const float* __restrict__ W2, const float* __restrict__ W3,
             _Float16* __restrict__ WT)
{
    const float* W = W0;
    if (blockIdx.z == 1) W = W1;
    if (blockIdx.z == 2) W = W2;
    if (blockIdx.z == 3) W = W3;
    _Float16* out = WT + ((size_t)blockIdx.z << 20);

    __shared__ float Ts[64][65];
    const int t = threadIdx.x;
    const int ebase = blockIdx.y * 64;
    const int fbase = blockIdx.x * 64;

    {
        const int r0 = (t >> 4) * 4;
        const int c0 = (t & 15) * 4;
#pragma unroll
        for (int r = 0; r < 4; ++r) {
            float4 v = *(const float4*)&W[(size_t)(ebase + r0 + r) * 1024 + fbase + c0];
            Ts[r0 + r][c0 + 0] = v.x;
            Ts[r0 + r][c0 + 1] = v.y;
            Ts[r0 + r][c0 + 2] = v.z;
            Ts[r0 + r][c0 + 3] = v.w;
        }
    }
    __syncthreads();

    const int f = t >> 2;
    const int eseg = (t & 3) * 16;
    half8 lo, hi;
#pragma unroll
    for (int j = 0; j < 8; ++j) lo[j] = (_Float16)Ts[eseg + j][f];
#pragma unroll
    for (int j = 0; j < 8; ++j) hi[j] = (_Float16)Ts[eseg + 8 + j][f];
    *(half8*)&out[(size_t)(fbase + f) * 1024 + ebase + eseg]     = lo;
    *(half8*)&out[(size_t)(fbase + f) * 1024 + ebase + eseg + 8] = hi;
}

// ---------------------------------------------------------------------------
// MFMA GEMM (f16): C[s][f] = sum_e A[s][e]*W[e][f] + bias[f]
// 64x64 tile, BK=32, 4 waves (2x2), 16x16x32_f16 frags, double-buffered LDS.
// MODE 0: fp32 out[s][f]
// MODE 1: f16 head-split: z=0,1 -> O[h][s][d]; z=2 -> transposed O[h][d][s]
// ---------------------------------------------------------------------------
template<int MODE>
__global__ __launch_bounds__(256)
void gemm_mfma(const _Float16* __restrict__ A,
               const _Float16* __restrict__ BtBase,
               const float* __restrict__ B0, const float* __restrict__ B1,
               const float* __restrict__ B2,
               void* __restrict__ O0p, void* __restrict__ O1p, void* __restrict__ O2p)
{
    const int z = blockIdx.z;
    const _Float16* Bt = BtBase + ((size_t)z << 20);
    const float* bias = B0; void* Op = O0p;
    if (z == 1) { bias = B1; Op = O1p; }
    if (z == 2) { bias = B2; Op = O2p; }

    __shared__ _Float16 As[2][64][40];
    __shared__ _Float16 Bs[2][64][40];

    const int t = threadIdx.x;
    const int lane = t & 63;
    const int w = t >> 6;
    const int w_r = w >> 1;
    const int w_c = w & 1;
    const int sbase = blockIdx.y * 64;
    const int fbase = blockIdx.x * 64;

    const int srow = t >> 2;
    const int skseg = (t & 3) * 8;

    f32x4 acc[2][2];
#pragma unroll
    for (int m = 0; m < 2; ++m)
#pragma unroll
        for (int n = 0; n < 2; ++n) acc[m][n] = (f32x4){0.f, 0.f, 0.f, 0.f};

    const int lr = lane & 15;
    const int lk = (lane >> 4) * 8;

    {
        *(half8*)&As[0][srow][skseg] = *(const half8*)&A [(size_t)(sbase + srow) * 1024 + skseg];
        *(half8*)&Bs[0][srow][skseg] = *(const half8*)&Bt[(size_t)(fbase + srow) * 1024 + skseg];
    }
    __syncthreads();

    for (int tile = 0; tile < 32; ++tile) {
        const int cur = tile & 1;
        if (tile < 31) {
            const int kb = (tile + 1) * 32;
            half8 av = *(const half8*)&A [(size_t)(sbase + srow) * 1024 + kb + skseg];
            half8 bv = *(const half8*)&Bt[(size_t)(fbase + srow) * 1024 + kb + skseg];
            *(half8*)&As[cur ^ 1][srow][skseg] = av;
            *(half8*)&Bs[cur ^ 1][srow][skseg] = bv;
        }
        half8 a0 = *(const half8*)&As[cur][w_r * 32 + 0  + lr][lk];
        half8 a1 = *(const half8*)&As[cur][w_r * 32 + 16 + lr][lk];
        half8 b0 = *(const half8*)&Bs[cur][w_c * 32 + 0  + lr][lk];
        half8 b1 = *(const half8*)&Bs[cur][w_c * 32 + 16 + lr][lk];
        acc[0][0] = __builtin_amdgcn_mfma_f32_16x16x32_f16(a0, b0, acc[0][0], 0, 0, 0);
        acc[0][1] = __builtin_amdgcn_mfma_f32_16x16x32_f16(a0, b1, acc[0][1], 0, 0, 0);
        acc[1][0] = __builtin_amdgcn_mfma_f32_16x16x32_f16(a1, b0, acc[1][0], 0, 0, 0);
        acc[1][1] = __builtin_amdgcn_mfma_f32_16x16x32_f16(a1, b1, acc[1][1], 0, 0, 0);
        __syncthreads();
    }

#pragma unroll
    for (int m = 0; m < 2; ++m) {
        const int row0 = sbase + w_r * 32 + m * 16 + (lane >> 4) * 4;
#pragma unroll
        for (int n = 0; n < 2; ++n) {
            const int col = fbase + w_c * 32 + n * 16 + (lane & 15);
            const float bval = bias[col];
            if (MODE == 0) {
                float* O = (float*)Op;
#pragma unroll
                for (int r = 0; r < 4; ++r)
                    O[(size_t)(row0 + r) * 1024 + col] = acc[m][n][r] + bval;
            } else {
                _Float16* O = (_Float16*)Op;
                const int hh = col >> 6;
                const int d = col & 63;
                if (z == 2) {   // V transposed: O[h][d][s]
                    half4 o;
#pragma unroll
                    for (int r = 0; r < 4; ++r) o[r] = (_Float16)(acc[m][n][r] + bval);
                    *(half4*)&O[((size_t)hh << 16) + (size_t)d * 1024 + row0] = o;
                } else {        // Q/K: O[h][s][d]
#pragma unroll
                    for (int r = 0; r < 4; ++r)
                        O[((size_t)hh << 16) + (size_t)(row0 + r) * 64 + d] =
                            (_Float16)(acc[m][n][r] + bval);
                }
            }
        }
    }
}

// ---------------------------------------------------------------------------
// Fused attention, SINGLE-PASS moment-PV, wave-pair moment split.
//   P(s) = 2^{abar s} (c0 + c1 s + c2 s^2 + c3 s^3);  O = sum_m c_m * PV_m
//   PV_m = sum_k s^m 2^{abar s} V[k]   (denominator-independent)
// 512 thr = 8 waves. Wave w: k-quarter kq=w&3 (256 k), moment pair mp=w>>2
// ({e, s e} or {s^2 e, s^3 e}). QK^T computed twice chip-wide (cheap MFMA);
// each wave holds only macc[2][4] = 32 acc regs -> ~100 live regs, and
// launch_bounds(512,2) caps at 256 so spill is IMPOSSIBLE (R6/R7/R9 lesson:
// every forced-occupancy/fat-acc config spilled; counters WRITE_SIZE must
// stay ~2MB this time). V loads hoisted: one vb pair feeds both moments.
// Epilogue: scalar moments M_m -> den_i -> wgt -> c_m -> weighted combine.
// deg-3 residual validated numerically in R9 (passed, absmax unchanged).
// XCD swizzle: 2 heads/XCD -> K/V L2-resident.
// ---------------------------------------------------------------------------
__global__ __launch_bounds__(512, 2)
void attn_k(const _Float16* __restrict__ Qg, const _Float16* __restrict__ Kg,
            const _Float16* __restrict__ Vg, const float* __restrict__ pm,
            const float* __restrict__ iwp, _Float16* __restrict__ comb)
{
    const int wg  = blockIdx.x;
    const int xcd = wg & 7;
    const int idx = wg >> 3;            // 0..127
    const int h   = xcd * 2 + (idx >> 6);
    const int qt  = idx & 63;           // 16-row q tile

    const int t = threadIdx.x;
    const int lane = t & 63;
    const int w = t >> 6;               // wave id
    const int kq = w & 3;               // k-quarter
    const int mp = w >> 2;              // moment pair: 0 -> {0,1}, 1 -> {2,3}
    const int lr = lane & 15;
    const int lg = lane >> 4;

    __shared__ union {
        _Float16 Ps[8][2][16][68];                        // [wave][mom-local][q][k64]
        struct { float Mom[8][16][2]; float Red[4][16][68]; } E;
    } U;
    __shared__ float sa[16], siw[16];
    __shared__ float gt[16][4];          // gamma_i^m / m!
    __shared__ float Ctab[16][4];        // c_m per q row

    if (t < 16) {
        float m = cosf(pm[t * NH + h]);
        sa[t] = m * m * 0.125f * 1.44269504f;   // a_i (log2 scale, on raw dot)
        siw[t] = iwp[t];
    }
    __syncthreads();

    float amin = sa[0], amax = sa[0];
#pragma unroll
    for (int i = 1; i < NWL; ++i) {
        amin = fminf(amin, sa[i]);
        amax = fmaxf(amax, sa[i]);
    }
    const float abar = 0.5f * (amin + amax);

    if (t < 16) {
        float g = (sa[t] - abar) * 0.69314718f;  // natural-log residual
        gt[t][0] = 1.f;
        gt[t][1] = g;
        gt[t][2] = g * g * 0.5f;
        gt[t][3] = g * g * g * (1.f / 6.f);
    }
    // gt read only after the post-k-loop barrier -> ordering safe

    // Q fragments (B-operand): col = q-local = lr, k-seg = lg*8
    const _Float16* Qrow = Qg + ((size_t)h << 16) + (size_t)(qt * 16 + lr) * 64;
    half8 q0 = *(const half8*)&Qrow[lg * 8];
    half8 q1 = *(const half8*)&Qrow[32 + lg * 8];

    const _Float16* Kqp = Kg + ((size_t)h << 16) + (size_t)(kq * 256) * 64;  // k-quarter
    const _Float16* Vh  = Vg + ((size_t)h << 16);                            // V^T [d][s]

    float Mlo = 0.f, Mhi = 0.f;
    f32x4 macc[2][4];
#pragma unroll
    for (int m = 0; m < 2; ++m)
#pragma unroll
        for (int n = 0; n < 4; ++n) macc[m][n] = (f32x4){0.f, 0.f, 0.f, 0.f};

    for (int ch = 0; ch < 4; ++ch) {
        // ---- QK^T + this wave's two moment powers for the 64k chunk ----
#pragma unroll
        for (int kf = 0; kf < 4; ++kf) {
            const _Float16* Kr = Kqp + (size_t)(ch * 64 + kf * 16 + lr) * 64;
            half8 a0 = *(const half8*)&Kr[lg * 8];
            half8 a1 = *(const half8*)&Kr[32 + lg * 8];
            f32x4 s2 = (f32x4){0.f, 0.f, 0.f, 0.f};
            s2 = __builtin_amdgcn_mfma_f32_16x16x32_f16(a0, q0, s2, 0, 0, 0);
            s2 = __builtin_amdgcn_mfma_f32_16x16x32_f16(a1, q1, s2, 0, 0, 0);
            half4 plo, phi;
#pragma unroll
            for (int r = 0; r < 4; ++r) {
                const float sv = s2[r];
                const float e = exp2f(abar * sv);
                float vlo, vhi;
                if (mp == 0) {           // wave-uniform branch (no divergence)
                    vlo = e;
                    vhi = e * sv;
                } else {
                    const float t2 = sv * sv;
                    vlo = e * t2;
                    vhi = vlo * sv;
                }
                Mlo += vlo;
                Mhi += vhi;
                plo[r] = (_Float16)vlo;
                phi[r] = (_Float16)vhi;
            }
            const int kl = kf * 16 + lg * 4;   // P[q=lr][k-local], wave-private
            *(half4*)&U.Ps[w][0][lr][kl] = plo;
            *(half4*)&U.Ps[w][1][lr][kl] = phi;
        }
        // ---- 2 moment-PV accumulations (same-wave LDS dep, lgkm waits) ----
        half8 pa00 = *(const half8*)&U.Ps[w][0][lr][lg * 8];
        half8 pa01 = *(const half8*)&U.Ps[w][0][lr][32 + lg * 8];
        half8 pa10 = *(const half8*)&U.Ps[w][1][lr][lg * 8];
        half8 pa11 = *(const half8*)&U.Ps[w][1][lr][32 + lg * 8];
        const int kcol = kq * 256 + ch * 64;
#pragma unroll
        for (int n = 0; n < 4; ++n) {
            const _Float16* Vr = Vh + (size_t)(n * 16 + lr) * 1024 + kcol;
            half8 vb0 = *(const half8*)&Vr[lg * 8];
            half8 vb1 = *(const half8*)&Vr[32 + lg * 8];
            macc[0][n] = __builtin_amdgcn_mfma_f32_16x16x32_f16(pa00, vb0, macc[0][n], 0, 0, 0);
            macc[0][n] = __builtin_amdgcn_mfma_f32_16x16x32_f16(pa01, vb1, macc[0][n], 0, 0, 0);
            macc[1][n] = __builtin_amdgcn_mfma_f32_16x16x32_f16(pa10, vb0, macc[1][n], 0, 0, 0);
            macc[1][n] = __builtin_amdgcn_mfma_f32_16x16x32_f16(pa11, vb1, macc[1][n], 0, 0, 0);
        }
    }
    __syncthreads();   // all waves done with Ps; union switches to E

    // ---- scalar moment reduce: sum over lg (k bits within wave) ----
#pragma unroll
    for (int off = 16; off < 64; off <<= 1) {
        Mlo += __shfl_xor(Mlo, off);
        Mhi += __shfl_xor(Mhi, off);
    }
    if (lg == 0) {
        U.E.Mom[w][lr][0] = Mlo;
        U.E.Mom[w][lr][1] = Mhi;
    }
    __syncthreads();

    // full moments per q-row = lr: M[m] from waves (m>>1)*4 + kq
    float Mf[4];
#pragma unroll
    for (int m = 0; m < 4; ++m) {
        const int wb = (m >> 1) * 4;
        const int j = m & 1;
        Mf[m] = U.E.Mom[wb][lr][j] + U.E.Mom[wb + 1][lr][j]
              + U.E.Mom[wb + 2][lr][j] + U.E.Mom[wb + 3][lr][j];
    }

    // den_i = sum_m gt[i][m] Mf[m]; wgt = iw/(16 den); c_m = sum_i wgt gt[i][m]
    float c0 = 0.f, c1 = 0.f, c2 = 0.f, c3 = 0.f;
#pragma unroll
    for (int i = 0; i < NWL; ++i) {
        float den = gt[i][0] * Mf[0];
        den = fmaf(gt[i][1], Mf[1], den);
        den = fmaf(gt[i][2], Mf[2], den);
        den = fmaf(gt[i][3], Mf[3], den);
        const float wgt = siw[i] / (den * 16.0f);
        c0 = fmaf(wgt, gt[i][0], c0);
        c1 = fmaf(wgt, gt[i][1], c1);
        c2 = fmaf(wgt, gt[i][2], c2);
        c3 = fmaf(wgt, gt[i][3], c3);
    }
    if (t < 16) {   // canonical writer per q row
        Ctab[t][0] = c0; Ctab[t][1] = c1; Ctab[t][2] = c2; Ctab[t][3] = c3;
    }
    __syncthreads();   // protects Mom reads -> Red writes, Ctab write -> read

    // ---- c-weighted combine; 2-stage Red over moment pairs, then k-quarters
    // macc C-layout: row q = lg*4 + r, col d = n*16 + lr
    if (mp == 1) {
#pragma unroll
        for (int n = 0; n < 4; ++n)
#pragma unroll
            for (int r = 0; r < 4; ++r) {
                const int q = lg * 4 + r;
                float o = Ctab[q][2] * macc[0][n][r];
                o = fmaf(Ctab[q][3], macc[1][n][r], o);
                U.E.Red[kq][q][n * 16 + lr] = o;
            }
    }
    __syncthreads();
    if (mp == 0) {
#pragma unroll
        for (int n = 0; n < 4; ++n)
#pragma unroll
            for (int r = 0; r < 4; ++r) {
                const int q = lg * 4 + r;
                float o = U.E.Red[kq][q][n * 16 + lr];
                o = fmaf(Ctab[q][0], macc[0][n][r], o);
                o = fmaf(Ctab[q][1], macc[1][n][r], o);
                U.E.Red[kq][q][n * 16 + lr] = o;
            }
    }
    __syncthreads();

    // ---- final reduce over k-quarters: t -> q = t>>5, d0 = (t&31)*2 ----
    {
        const int q = t >> 5;
        const int d0 = (t & 31) * 2;
        float s0 = U.E.Red[0][q][d0] + U.E.Red[1][q][d0]
                 + U.E.Red[2][q][d0] + U.E.Red[3][q][d0];
        float s1 = U.E.Red[0][q][d0 + 1] + U.E.Red[1][q][d0 + 1]
                 + U.E.Red[2][q][d0 + 1] + U.E.Red[3][q][d0 + 1];
        comb[(size_t)(qt * 16 + q) * 1024 + h * 64 + d0]     = (_Float16)s0;
        comb[(size_t)(qt * 16 + q) * 1024 + h * 64 + d0 + 1] = (_Float16)s1;
    }
}

// ---------------------------------------------------------------------------
extern "C" void kernel_launch(void* const* d_in, const int* in_sizes, int n_in,
                              void* d_out, int out_size, void* d_ws, size_t ws_size,
                              hipStream_t stream)
{
    const float* x  = (const float*)d_in[0];
    const float* Wq = (const float*)d_in[1];
    const float* bq = (const float*)d_in[2];
    const float* Wk = (const float*)d_in[3];
    const float* bk = (const float*)d_in[4];
    const float* Wv = (const float*)d_in[5];
    const float* bv = (const float*)d_in[6];
    const float* Wo = (const float*)d_in[7];
    const float* bo = (const float*)d_in[8];
    const float* pm = (const float*)d_in[9];
    const float* iw = (const float*)d_in[10];
    float* out = (float*)d_out;

    // ws (f16 elems): Xh 1M (reused as comb) | WT 4M | Q 1M | K 1M | Vt 1M = 16 MB
    _Float16* Xh = (_Float16*)d_ws;
    _Float16* WT = Xh + (1u << 20);
    _Float16* Qh = WT + (4u << 20);
    _Float16* Kh = Qh + (1u << 20);
    _Float16* Vt = Kh + (1u << 20);
    _Float16* comb = Xh;   // Xh dead after QKV GEMM

    dim3 blk(256);
    cast_x_k<<<dim3(512), blk, 0, stream>>>(x, Xh);
    castT_w<<<dim3(16, 16, 4), blk, 0, stream>>>(Wq, Wk, Wv, Wo, WT);
    gemm_mfma<1><<<dim3(16, 16, 3), blk, 0, stream>>>(Xh, WT, bq, bk, bv, Qh, Kh, Vt);
    attn_k<<<dim3(1024), dim3(512), 0, stream>>>(Qh, Kh, Vt, pm, iw, comb);
    gemm_mfma<0><<<dim3(16, 16, 1), blk, 0, stream>>>(
        comb, WT + (3u << 20), bo, bo, bo, out, out, out);
}

// Round 12
// 112.096 us; speedup vs baseline: 1.1333x; 1.0447x over previous
//
#include <hip/hip_runtime.h>
#include <hip/hip_fp16.h>
#include <math.h>

#define NH 16
#define NWL 16

typedef _Float16 half8 __attribute__((ext_vector_type(8)));
typedef _Float16 half4 __attribute__((ext_vector_type(4)));
typedef float f32x4 __attribute__((ext_vector_type(4)));

// ---------------------------------------------------------------------------
// cast x (fp32 -> f16), 8 elems/thread
// ---------------------------------------------------------------------------
__global__ __launch_bounds__(256)
void cast_x_k(const float* __restrict__ X, _Float16* __restrict__ Xh)
{
    const int i = (blockIdx.x * 256 + threadIdx.x) * 8;
    float4 v0 = *(const float4*)&X[i];
    float4 v1 = *(const float4*)&X[i + 4];
    half8 o;
    o[0] = (_Float16)v0.x; o[1] = (_Float16)v0.y; o[2] = (_Float16)v0.z; o[3] = (_Float16)v0.w;
    o[4] = (_Float16)v1.x; o[5] = (_Float16)v1.y; o[6] = (_Float16)v1.z; o[7] = (_Float16)v1.w;
    *(half8*)&Xh[i] = o;
}

// ---------------------------------------------------------------------------
// cast + transpose W[e][f] -> WT[f][e] f16, 64x64 tiles, z picks which W
// ---------------------------------------------------------------------------
__global__ __launch_bounds__(256)
void castT_w(const float* __restrict__ W0, const float* __restrict__ W1,
             const float* __restrict__ W2, const float* __restrict__ W3,
             _Float16* __restrict__ WT)
{
    const float* W = W0;
    if (blockIdx.z == 1) W = W1;
    if (blockIdx.z == 2) W = W2;
    if (blockIdx.z == 3) W = W3;
    _Float16* out = WT + ((size_t)blockIdx.z << 20);

    __shared__ float Ts[64][65];
    const int t = threadIdx.x;
    const int ebase = blockIdx.y * 64;
    const int fbase = blockIdx.x * 64;

    {
        const int r0 = (t >> 4) * 4;
        const int c0 = (t & 15) * 4;
#pragma unroll
        for (int r = 0; r < 4; ++r) {
            float4 v = *(const float4*)&W[(size_t)(ebase + r0 + r) * 1024 + fbase + c0];
            Ts[r0 + r][c0 + 0] = v.x;
            Ts[r0 + r][c0 + 1] = v.y;
            Ts[r0 + r][c0 + 2] = v.z;
            Ts[r0 + r][c0 + 3] = v.w;
        }
    }
    __syncthreads();

    const int f = t >> 2;
    const int eseg = (t & 3) * 16;
    half8 lo, hi;
#pragma unroll
    for (int j = 0; j < 8; ++j) lo[j] = (_Float16)Ts[eseg + j][f];
#pragma unroll
    for (int j = 0; j < 8; ++j) hi[j] = (_Float16)Ts[eseg + 8 + j][f];
    *(half8*)&out[(size_t)(fbase + f) * 1024 + ebase + eseg]     = lo;
    *(half8*)&out[(size_t)(fbase + f) * 1024 + ebase + eseg + 8] = hi;
}

// ---------------------------------------------------------------------------
// MFMA GEMM (f16): C[s][f] = sum_e A[s][e]*W[e][f] + bias[f]
// 64x64 tile, BK=32, 4 waves (2x2), 16x16x32_f16 frags, double-buffered LDS.
// MODE 0: fp32 out[s][f]
// MODE 1: f16 head-split: z=0,1 -> O[h][s][d]; z=2 -> transposed O[h][d][s]
// ---------------------------------------------------------------------------
template<int MODE>
__global__ __launch_bounds__(256)
void gemm_mfma(const _Float16* __restrict__ A,
               const _Float16* __restrict__ BtBase,
               const float* __restrict__ B0, const float* __restrict__ B1,
               const float* __restrict__ B2,
               void* __restrict__ O0p, void* __restrict__ O1p, void* __restrict__ O2p)
{
    const int z = blockIdx.z;
    const _Float16* Bt = BtBase + ((size_t)z << 20);
    const float* bias = B0; void* Op = O0p;
    if (z == 1) { bias = B1; Op = O1p; }
    if (z == 2) { bias = B2; Op = O2p; }

    __shared__ _Float16 As[2][64][40];
    __shared__ _Float16 Bs[2][64][40];

    const int t = threadIdx.x;
    const int lane = t & 63;
    const int w = t >> 6;
    const int w_r = w >> 1;
    const int w_c = w & 1;
    const int sbase = blockIdx.y * 64;
    const int fbase = blockIdx.x * 64;

    const int srow = t >> 2;
    const int skseg = (t & 3) * 8;

    f32x4 acc[2][2];
#pragma unroll
    for (int m = 0; m < 2; ++m)
#pragma unroll
        for (int n = 0; n < 2; ++n) acc[m][n] = (f32x4){0.f, 0.f, 0.f, 0.f};

    const int lr = lane & 15;
    const int lk = (lane >> 4) * 8;

    {
        *(half8*)&As[0][srow][skseg] = *(const half8*)&A [(size_t)(sbase + srow) * 1024 + skseg];
        *(half8*)&Bs[0][srow][skseg] = *(const half8*)&Bt[(size_t)(fbase + srow) * 1024 + skseg];
    }
    __syncthreads();

    for (int tile = 0; tile < 32; ++tile) {
        const int cur = tile & 1;
        if (tile < 31) {
            const int kb = (tile + 1) * 32;
            half8 av = *(const half8*)&A [(size_t)(sbase + srow) * 1024 + kb + skseg];
            half8 bv = *(const half8*)&Bt[(size_t)(fbase + srow) * 1024 + kb + skseg];
            *(half8*)&As[cur ^ 1][srow][skseg] = av;
            *(half8*)&Bs[cur ^ 1][srow][skseg] = bv;
        }
        half8 a0 = *(const half8*)&As[cur][w_r * 32 + 0  + lr][lk];
        half8 a1 = *(const half8*)&As[cur][w_r * 32 + 16 + lr][lk];
        half8 b0 = *(const half8*)&Bs[cur][w_c * 32 + 0  + lr][lk];
        half8 b1 = *(const half8*)&Bs[cur][w_c * 32 + 16 + lr][lk];
        acc[0][0] = __builtin_amdgcn_mfma_f32_16x16x32_f16(a0, b0, acc[0][0], 0, 0, 0);
        acc[0][1] = __builtin_amdgcn_mfma_f32_16x16x32_f16(a0, b1, acc[0][1], 0, 0, 0);
        acc[1][0] = __builtin_amdgcn_mfma_f32_16x16x32_f16(a1, b0, acc[1][0], 0, 0, 0);
        acc[1][1] = __builtin_amdgcn_mfma_f32_16x16x32_f16(a1, b1, acc[1][1], 0, 0, 0);
        __syncthreads();
    }

#pragma unroll
    for (int m = 0; m < 2; ++m) {
        const int row0 = sbase + w_r * 32 + m * 16 + (lane >> 4) * 4;
#pragma unroll
        for (int n = 0; n < 2; ++n) {
            const int col = fbase + w_c * 32 + n * 16 + (lane & 15);
            const float bval = bias[col];
            if (MODE == 0) {
                float* O = (float*)Op;
#pragma unroll
                for (int r = 0; r < 4; ++r)
                    O[(size_t)(row0 + r) * 1024 + col] = acc[m][n][r] + bval;
            } else {
                _Float16* O = (_Float16*)Op;
                const int hh = col >> 6;
                const int d = col & 63;
                if (z == 2) {   // V transposed: O[h][d][s]
                    half4 o;
#pragma unroll
                    for (int r = 0; r < 4; ++r) o[r] = (_Float16)(acc[m][n][r] + bval);
                    *(half4*)&O[((size_t)hh << 16) + (size_t)d * 1024 + row0] = o;
                } else {        // Q/K: O[h][s][d]
#pragma unroll
                    for (int r = 0; r < 4; ++r)
                        O[((size_t)hh << 16) + (size_t)(row0 + r) * 64 + d] =
                            (_Float16)(acc[m][n][r] + bval);
                }
            }
        }
    }
}

// ---------------------------------------------------------------------------
// ATTENTION, 3-kernel split, 20 MB ws footprint (R11 lesson: 33 MB ws was
// never validated -> heap overflow -> NaN. Max proven ws = 23 MB (R2)).
//
// Math (deg-3 moment form, validated R9/R10):
//   P(s) = 2^{abar s} (c0 + c1 s + c2 s^2 + c3 s^3),  O = sum_m c_m * PV_m
//   den_i = sum_m gt[i][m] M_m,   M_m = sum_k s^m 2^{abar s}
//
// mom_k : 4096 blocks (h, qt16, kq256), 4 waves x 64 k. QK^T + moments only
//         (~45 regs, 8 w/SIMD). Mpart -> dead WT slab 0 (1 MB, no new ws).
// pvm_k : 2048 blocks (h, qt16, khalf512), 4 waves x 128 k. Prologue solves
//         c from Mpart; sweep QK^T -> P -> PV (16 acc regs); block LDS
//         reduce -> ONE f16 partial per output -> Opart 4 MB.
// ored_k: sum 2 f16 partials -> comb.
// ---------------------------------------------------------------------------
__global__ __launch_bounds__(256, 4)
void mom_k(const _Float16* __restrict__ Qg, const _Float16* __restrict__ Kg,
           const float* __restrict__ pm, float* __restrict__ Mpart)
{
    const int wg  = blockIdx.x;
    const int xcd = wg & 7;
    const int idx = wg >> 3;            // 0..511
    const int h   = xcd * 2 + (idx >> 8);
    const int rem = idx & 255;
    const int qt  = rem >> 2;           // 0..63
    const int kq  = rem & 3;            // k-quarter

    const int t = threadIdx.x;
    const int lane = t & 63;
    const int w = t >> 6;
    const int lr = lane & 15;
    const int lg = lane >> 4;

    __shared__ float sa[16];
    __shared__ float MomL[4][16][4];

    if (t < 16) {
        float m = cosf(pm[t * NH + h]);
        sa[t] = m * m * 0.125f * 1.44269504f;   // a_i in log2 scale
    }
    __syncthreads();

    float amin = sa[0], amax = sa[0];
#pragma unroll
    for (int i = 1; i < NWL; ++i) {
        amin = fminf(amin, sa[i]);
        amax = fmaxf(amax, sa[i]);
    }
    const float abar = 0.5f * (amin + amax);

    const _Float16* Qrow = Qg + ((size_t)h << 16) + (size_t)(qt * 16 + lr) * 64;
    half8 q0 = *(const half8*)&Qrow[lg * 8];
    half8 q1 = *(const half8*)&Qrow[32 + lg * 8];

    const _Float16* Kbase = Kg + ((size_t)h << 16) + (size_t)(kq * 256 + w * 64) * 64;

    float M0 = 0.f, M1 = 0.f, M2 = 0.f, M3 = 0.f;
#pragma unroll
    for (int kf = 0; kf < 4; ++kf) {
        const _Float16* Kr = Kbase + (size_t)(kf * 16 + lr) * 64;
        half8 a0 = *(const half8*)&Kr[lg * 8];
        half8 a1 = *(const half8*)&Kr[32 + lg * 8];
        f32x4 s2 = (f32x4){0.f, 0.f, 0.f, 0.f};
        s2 = __builtin_amdgcn_mfma_f32_16x16x32_f16(a0, q0, s2, 0, 0, 0);
        s2 = __builtin_amdgcn_mfma_f32_16x16x32_f16(a1, q1, s2, 0, 0, 0);
#pragma unroll
        for (int r = 0; r < 4; ++r) {
            const float sv = s2[r];
            const float e  = exp2f(abar * sv);
            const float es = e * sv;
            const float t2 = sv * sv;
            M0 += e;
            M1 += es;
            M2 += e * t2;
            M3 += es * t2;
        }
    }

#pragma unroll
    for (int off = 16; off < 64; off <<= 1) {
        M0 += __shfl_xor(M0, off);
        M1 += __shfl_xor(M1, off);
        M2 += __shfl_xor(M2, off);
        M3 += __shfl_xor(M3, off);
    }
    if (lg == 0) {
        MomL[w][lr][0] = M0;
        MomL[w][lr][1] = M1;
        MomL[w][lr][2] = M2;
        MomL[w][lr][3] = M3;
    }
    __syncthreads();

    if (t < 64) {
        const int row = t >> 2;
        const int m = t & 3;
        const float s = MomL[0][row][m] + MomL[1][row][m]
                      + MomL[2][row][m] + MomL[3][row][m];
        // Mpart[h][qt][kq][row][m]
        Mpart[(((size_t)(h * 64 + qt) * 4 + kq) * 16 + row) * 4 + m] = s;
    }
}

__global__ __launch_bounds__(256, 4)
void pvm_k(const _Float16* __restrict__ Qg, const _Float16* __restrict__ Kg,
           const _Float16* __restrict__ Vg, const float* __restrict__ pm,
           const float* __restrict__ iwp, const float* __restrict__ Mpart,
           _Float16* __restrict__ Opart)
{
    const int wg  = blockIdx.x;
    const int xcd = wg & 7;
    const int idx = wg >> 3;            // 0..255
    const int h   = xcd * 2 + (idx >> 7);
    const int rem = idx & 127;
    const int qt  = rem >> 1;           // 0..63
    const int kh  = rem & 1;            // k-half (512 k)

    const int t = threadIdx.x;
    const int lane = t & 63;
    const int w = t >> 6;               // wave owns 128 k
    const int lr = lane & 15;
    const int lg = lane >> 4;

    __shared__ union {
        _Float16 Ps[4][16][68];    // per-wave P chunk during sweep
        float Red[4][16][68];      // O-partial reduce after barrier
    } U;
    __shared__ float sa[16], siw[16];
    __shared__ float gt[16][4];
    __shared__ float Ctab[16][4];

    if (t < 16) {
        float m = cosf(pm[t * NH + h]);
        sa[t] = m * m * 0.125f * 1.44269504f;
        siw[t] = iwp[t];
    }
    __syncthreads();

    float amin = sa[0], amax = sa[0];
#pragma unroll
    for (int i = 1; i < NWL; ++i) {
        amin = fminf(amin, sa[i]);
        amax = fmaxf(amax, sa[i]);
    }
    const float abar = 0.5f * (amin + amax);

    if (t < 16) {
        float g = (sa[t] - abar) * 0.69314718f;
        gt[t][0] = 1.f;
        gt[t][1] = g;
        gt[t][2] = g * g * 0.5f;
        gt[t][3] = g * g * g * (1.f / 6.f);
    }
    __syncthreads();

    if (t < 16) {
        // full moments for q-row t: sum Mpart over the 4 k-quarters
        const float* mp = &Mpart[(size_t)(h * 64 + qt) * 256 + t * 4];
        float Mf0 = 0.f, Mf1 = 0.f, Mf2 = 0.f, Mf3 = 0.f;
#pragma unroll
        for (int k2 = 0; k2 < 4; ++k2) {
            Mf0 += mp[k2 * 64 + 0];
            Mf1 += mp[k2 * 64 + 1];
            Mf2 += mp[k2 * 64 + 2];
            Mf3 += mp[k2 * 64 + 3];
        }
        float c0 = 0.f, c1 = 0.f, c2 = 0.f, c3 = 0.f;
#pragma unroll
        for (int i = 0; i < NWL; ++i) {
            float den = gt[i][0] * Mf0;
            den = fmaf(gt[i][1], Mf1, den);
            den = fmaf(gt[i][2], Mf2, den);
            den = fmaf(gt[i][3], Mf3, den);
            const float wgt = siw[i] / (den * 16.0f);
            c0 = fmaf(wgt, gt[i][0], c0);
            c1 = fmaf(wgt, gt[i][1], c1);
            c2 = fmaf(wgt, gt[i][2], c2);
            c3 = fmaf(wgt, gt[i][3], c3);
        }
        Ctab[t][0] = c0; Ctab[t][1] = c1; Ctab[t][2] = c2; Ctab[t][3] = c3;
    }
    __syncthreads();

    const float c0 = Ctab[lr][0], c1 = Ctab[lr][1];
    const float c2 = Ctab[lr][2], c3 = Ctab[lr][3];

    const _Float16* Qrow = Qg + ((size_t)h << 16) + (size_t)(qt * 16 + lr) * 64;
    half8 q0 = *(const half8*)&Qrow[lg * 8];
    half8 q1 = *(const half8*)&Qrow[32 + lg * 8];

    const int k0 = kh * 512 + w * 128;                 // wave's 128-k window
    const _Float16* Kbase = Kg + ((size_t)h << 16) + (size_t)k0 * 64;
    const _Float16* Vh = Vg + ((size_t)h << 16);       // V^T [d][s]

    f32x4 oacc[4];
#pragma unroll
    for (int n = 0; n < 4; ++n) oacc[n] = (f32x4){0.f, 0.f, 0.f, 0.f};

#pragma unroll
    for (int ch = 0; ch < 2; ++ch) {
        // ---- QK^T -> P -> Ps for this 64k chunk ----
#pragma unroll
        for (int kf = 0; kf < 4; ++kf) {
            const _Float16* Kr = Kbase + (size_t)(ch * 64 + kf * 16 + lr) * 64;
            half8 a0 = *(const half8*)&Kr[lg * 8];
            half8 a1 = *(const half8*)&Kr[32 + lg * 8];
            f32x4 s2 = (f32x4){0.f, 0.f, 0.f, 0.f};
            s2 = __builtin_amdgcn_mfma_f32_16x16x32_f16(a0, q0, s2, 0, 0, 0);
            s2 = __builtin_amdgcn_mfma_f32_16x16x32_f16(a1, q1, s2, 0, 0, 0);
            half4 ph;
#pragma unroll
            for (int r = 0; r < 4; ++r) {
                const float sv = s2[r];
                const float e = exp2f(abar * sv);
                float poly = fmaf(c3, sv, c2);
                poly = fmaf(poly, sv, c1);
                poly = fmaf(poly, sv, c0);
                ph[r] = (_Float16)(e * poly);
            }
            *(half4*)&U.Ps[w][lr][kf * 16 + lg * 4] = ph;   // wave-private
        }
        // ---- PV over this 64k chunk (same-wave LDS dep) ----
        half8 pa0 = *(const half8*)&U.Ps[w][lr][lg * 8];
        half8 pa1 = *(const half8*)&U.Ps[w][lr][32 + lg * 8];
        const int kcol = k0 + ch * 64;
#pragma unroll
        for (int n = 0; n < 4; ++n) {
            const _Float16* Vr = Vh + (size_t)(n * 16 + lr) * 1024 + kcol;
            half8 vb0 = *(const half8*)&Vr[lg * 8];
            half8 vb1 = *(const half8*)&Vr[32 + lg * 8];
            oacc[n] = __builtin_amdgcn_mfma_f32_16x16x32_f16(pa0, vb0, oacc[n], 0, 0, 0);
            oacc[n] = __builtin_amdgcn_mfma_f32_16x16x32_f16(pa1, vb1, oacc[n], 0, 0, 0);
        }
    }
    __syncthreads();   // all waves done with Ps; union switches to Red

    // oacc C-layout: row q = lg*4+r, col d = n*16+lr
#pragma unroll
    for (int n = 0; n < 4; ++n)
#pragma unroll
        for (int r = 0; r < 4; ++r)
            U.Red[w][lg * 4 + r][n * 16 + lr] = oacc[n][r];
    __syncthreads();

    // block partial over its 512 k: thread t -> q = t>>4, d0 = (t&15)*4
    {
        const int q = t >> 4;
        const int d0 = (t & 15) * 4;
        f32x4 s0 = *(const f32x4*)&U.Red[0][q][d0];
        f32x4 s1 = *(const f32x4*)&U.Red[1][q][d0];
        f32x4 s2v = *(const f32x4*)&U.Red[2][q][d0];
        f32x4 s3 = *(const f32x4*)&U.Red[3][q][d0];
        f32x4 sum = s0 + s1 + s2v + s3;
        half4 o;
#pragma unroll
        for (int j = 0; j < 4; ++j) o[j] = (_Float16)sum[j];
        // Opart[kh][h][qt][q][d], plane = 1M f16
        _Float16* dst = &Opart[(((size_t)kh * 16 + h) * 64 + qt) * 1024 + q * 64 + d0];
        *(half4*)dst = o;
    }
}

__global__ __launch_bounds__(256)
void ored_k(const _Float16* __restrict__ Opart, _Float16* __restrict__ comb)
{
    const int gid = blockIdx.x * 256 + threadIdx.x;   // 0..262143
    const int h  = gid >> 14;
    const int r  = gid & 16383;
    const int qt = r >> 8;
    const int q  = (r >> 4) & 15;
    const int d0 = (r & 15) * 4;
    const size_t base = (((size_t)h * 64 + qt) * 16 + q) * 64 + d0;
    const size_t plane = (size_t)16 * 64 * 16 * 64;   // 1,048,576 f16
    half4 a = *(const half4*)&Opart[base];
    half4 b = *(const half4*)&Opart[base + plane];
    half4 o;
#pragma unroll
    for (int j = 0; j < 4; ++j) o[j] = (_Float16)((float)a[j] + (float)b[j]);
    *(half4*)&comb[(size_t)(qt * 16 + q) * 1024 + h * 64 + d0] = o;
}

// ---------------------------------------------------------------------------
extern "C" void kernel_launch(void* const* d_in, const int* in_sizes, int n_in,
                              void* d_out, int out_size, void* d_ws, size_t ws_size,
                              hipStream_t stream)
{
    const float* x  = (const float*)d_in[0];
    const float* Wq = (const float*)d_in[1];
    const float* bq = (const float*)d_in[2];
    const float* Wk = (const float*)d_in[3];
    const float* bk = (const float*)d_in[4];
    const float* Wv = (const float*)d_in[5];
    const float* bv = (const float*)d_in[6];
    const float* Wo = (const float*)d_in[7];
    const float* bo = (const float*)d_in[8];
    const float* pm = (const float*)d_in[9];
    const float* iw = (const float*)d_in[10];
    float* out = (float*)d_out;

    // ws layout (bytes):
    //   [ 0, 2M)  Xh f16 (reused as comb)
    //   [ 2,10M)  WT f16 (4 slabs; slab0 reused as Mpart after QKV GEMM)
    //   [10,12M)  Qh   [12,14M) Kh   [14,16M) Vt
    //   [16,20M)  Opart f16 [2][1M]
    // total 20 MB (max validated ws = 23 MB, R2)
    _Float16* Xh = (_Float16*)d_ws;
    _Float16* WT = Xh + (1u << 20);
    _Float16* Qh = WT + (4u << 20);
    _Float16* Kh = Qh + (1u << 20);
    _Float16* Vt = Kh + (1u << 20);
    _Float16* Opart = Vt + (1u << 20);
    float* Mpart = (float*)WT;          // dead Wq-slab after QKV GEMM
    _Float16* comb = Xh;                // Xh dead after QKV GEMM

    dim3 blk(256);
    cast_x_k<<<dim3(512), blk, 0, stream>>>(x, Xh);
    castT_w<<<dim3(16, 16, 4), blk, 0, stream>>>(Wq, Wk, Wv, Wo, WT);
    gemm_mfma<1><<<dim3(16, 16, 3), blk, 0, stream>>>(Xh, WT, bq, bk, bv, Qh, Kh, Vt);
    mom_k<<<dim3(4096), blk, 0, stream>>>(Qh, Kh, pm, Mpart);
    pvm_k<<<dim3(2048), blk, 0, stream>>>(Qh, Kh, Vt, pm, iw, Mpart, Opart);
    ored_k<<<dim3(1024), blk, 0, stream>>>(Opart, comb);
    gemm_mfma<0><<<dim3(16, 16, 1), blk, 0, stream>>>(
        comb, WT + (3u << 20), bo, bo, bo, out, out, out);
}

// Round 13
// 101.380 us; speedup vs baseline: 1.2531x; 1.1057x over previous
//
#include <hip/hip_runtime.h>
#include <hip/hip_fp16.h>
#include <math.h>

#define NH 16
#define NWL 16

typedef _Float16 half8 __attribute__((ext_vector_type(8)));
typedef _Float16 half4 __attribute__((ext_vector_type(4)));
typedef float f32x4 __attribute__((ext_vector_type(4)));

// ---------------------------------------------------------------------------
// cast x (fp32 -> f16), 8 elems/thread
// ---------------------------------------------------------------------------
__global__ __launch_bounds__(256)
void cast_x_k(const float* __restrict__ X, _Float16* __restrict__ Xh)
{
    const int i = (blockIdx.x * 256 + threadIdx.x) * 8;
    float4 v0 = *(const float4*)&X[i];
    float4 v1 = *(const float4*)&X[i + 4];
    half8 o;
    o[0] = (_Float16)v0.x; o[1] = (_Float16)v0.y; o[2] = (_Float16)v0.z; o[3] = (_Float16)v0.w;
    o[4] = (_Float16)v1.x; o[5] = (_Float16)v1.y; o[6] = (_Float16)v1.z; o[7] = (_Float16)v1.w;
    *(half8*)&Xh[i] = o;
}

// ---------------------------------------------------------------------------
// cast + transpose W[e][f] -> WT[f][e] f16, 64x64 tiles, z picks which W
// ---------------------------------------------------------------------------
__global__ __launch_bounds__(256)
void castT_w(const float* __restrict__ W0, const float* __restrict__ W1,
             const float* __restrict__ W2, const float* __restrict__ W3,
             _Float16* __restrict__ WT)
{
    const float* W = W0;
    if (blockIdx.z == 1) W = W1;
    if (blockIdx.z == 2) W = W2;
    if (blockIdx.z == 3) W = W3;
    _Float16* out = WT + ((size_t)blockIdx.z << 20);

    __shared__ float Ts[64][65];
    const int t = threadIdx.x;
    const int ebase = blockIdx.y * 64;
    const int fbase = blockIdx.x * 64;

    {
        const int r0 = (t >> 4) * 4;
        const int c0 = (t & 15) * 4;
#pragma unroll
        for (int r = 0; r < 4; ++r) {
            float4 v = *(const float4*)&W[(size_t)(ebase + r0 + r) * 1024 + fbase + c0];
            Ts[r0 + r][c0 + 0] = v.x;
            Ts[r0 + r][c0 + 1] = v.y;
            Ts[r0 + r][c0 + 2] = v.z;
            Ts[r0 + r][c0 + 3] = v.w;
        }
    }
    __syncthreads();

    const int f = t >> 2;
    const int eseg = (t & 3) * 16;
    half8 lo, hi;
#pragma unroll
    for (int j = 0; j < 8; ++j) lo[j] = (_Float16)Ts[eseg + j][f];
#pragma unroll
    for (int j = 0; j < 8; ++j) hi[j] = (_Float16)Ts[eseg + 8 + j][f];
    *(half8*)&out[(size_t)(fbase + f) * 1024 + ebase + eseg]     = lo;
    *(half8*)&out[(size_t)(fbase + f) * 1024 + ebase + eseg + 8] = hi;
}

// ---------------------------------------------------------------------------
// MFMA GEMM (f16): C[s][f] = sum_e A[s][e]*W[e][f] + bias[f]
// 64x64 tile, BK=32, 4 waves (2x2), 16x16x32_f16 frags, double-buffered LDS.
// MODE 0: fp32 out[s][f]
// MODE 1: f16 head-split: z=0,1 -> O[h][s][d]; z=2 -> transposed O[h][d][s]
// ---------------------------------------------------------------------------
template<int MODE>
__global__ __launch_bounds__(256)
void gemm_mfma(const _Float16* __restrict__ A,
               const _Float16* __restrict__ BtBase,
               const float* __restrict__ B0, const float* __restrict__ B1,
               const float* __restrict__ B2,
               void* __restrict__ O0p, void* __restrict__ O1p, void* __restrict__ O2p)
{
    const int z = blockIdx.z;
    const _Float16* Bt = BtBase + ((size_t)z << 20);
    const float* bias = B0; void* Op = O0p;
    if (z == 1) { bias = B1; Op = O1p; }
    if (z == 2) { bias = B2; Op = O2p; }

    __shared__ _Float16 As[2][64][40];
    __shared__ _Float16 Bs[2][64][40];

    const int t = threadIdx.x;
    const int lane = t & 63;
    const int w = t >> 6;
    const int w_r = w >> 1;
    const int w_c = w & 1;
    const int sbase = blockIdx.y * 64;
    const int fbase = blockIdx.x * 64;

    const int srow = t >> 2;
    const int skseg = (t & 3) * 8;

    f32x4 acc[2][2];
#pragma unroll
    for (int m = 0; m < 2; ++m)
#pragma unroll
        for (int n = 0; n < 2; ++n) acc[m][n] = (f32x4){0.f, 0.f, 0.f, 0.f};

    const int lr = lane & 15;
    const int lk = (lane >> 4) * 8;

    {
        *(half8*)&As[0][srow][skseg] = *(const half8*)&A [(size_t)(sbase + srow) * 1024 + skseg];
        *(half8*)&Bs[0][srow][skseg] = *(const half8*)&Bt[(size_t)(fbase + srow) * 1024 + skseg];
    }
    __syncthreads();

    for (int tile = 0; tile < 32; ++tile) {
        const int cur = tile & 1;
        if (tile < 31) {
            const int kb = (tile + 1) * 32;
            half8 av = *(const half8*)&A [(size_t)(sbase + srow) * 1024 + kb + skseg];
            half8 bv = *(const half8*)&Bt[(size_t)(fbase + srow) * 1024 + kb + skseg];
            *(half8*)&As[cur ^ 1][srow][skseg] = av;
            *(half8*)&Bs[cur ^ 1][srow][skseg] = bv;
        }
        half8 a0 = *(const half8*)&As[cur][w_r * 32 + 0  + lr][lk];
        half8 a1 = *(const half8*)&As[cur][w_r * 32 + 16 + lr][lk];
        half8 b0 = *(const half8*)&Bs[cur][w_c * 32 + 0  + lr][lk];
        half8 b1 = *(const half8*)&Bs[cur][w_c * 32 + 16 + lr][lk];
        acc[0][0] = __builtin_amdgcn_mfma_f32_16x16x32_f16(a0, b0, acc[0][0], 0, 0, 0);
        acc[0][1] = __builtin_amdgcn_mfma_f32_16x16x32_f16(a0, b1, acc[0][1], 0, 0, 0);
        acc[1][0] = __builtin_amdgcn_mfma_f32_16x16x32_f16(a1, b0, acc[1][0], 0, 0, 0);
        acc[1][1] = __builtin_amdgcn_mfma_f32_16x16x32_f16(a1, b1, acc[1][1], 0, 0, 0);
        __syncthreads();
    }

#pragma unroll
    for (int m = 0; m < 2; ++m) {
        const int row0 = sbase + w_r * 32 + m * 16 + (lane >> 4) * 4;
#pragma unroll
        for (int n = 0; n < 2; ++n) {
            const int col = fbase + w_c * 32 + n * 16 + (lane & 15);
            const float bval = bias[col];
            if (MODE == 0) {
                float* O = (float*)Op;
#pragma unroll
                for (int r = 0; r < 4; ++r)
                    O[(size_t)(row0 + r) * 1024 + col] = acc[m][n][r] + bval;
            } else {
                _Float16* O = (_Float16*)Op;
                const int hh = col >> 6;
                const int d = col & 63;
                if (z == 2) {   // V transposed: O[h][d][s]
                    half4 o;
#pragma unroll
                    for (int r = 0; r < 4; ++r) o[r] = (_Float16)(acc[m][n][r] + bval);
                    *(half4*)&O[((size_t)hh << 16) + (size_t)d * 1024 + row0] = o;
                } else {        // Q/K: O[h][s][d]
#pragma unroll
                    for (int r = 0; r < 4; ++r)
                        O[((size_t)hh << 16) + (size_t)(row0 + r) * 64 + d] =
                            (_Float16)(acc[m][n][r] + bval);
                }
            }
        }
    }
}

// ---------------------------------------------------------------------------
// Fused attention, SINGLE-PASS moment-PV (R9 algorithm, register-fixed).
//   P(s) = 2^{abar s}(c0 + c1 s + c2 s^2 + c3 s^3);  O = sum_m c_m * PV_m
//   PV_m = sum_k s^m 2^{abar s} V[k]   (denominator-independent)
// One k-sweep: QK^T -> powers {e,se,s2e,s3e} -> f16 -> 4 moment-PV MFMA
// accums + scalar moments. Epilogue solves den/wgt/c and combines.
//
// R9 RETRO: failed on registers only — PV loop was m-outer/n-inner, so V
// was CSE-hoisted (32 half8 = 64 VGPR live) + macc 64 acc > 128 cap ->
// per-iter accumulator spill (330 MB scratch traffic). Fix here:
//   (1) n-OUTER / m-INNER: V loaded once per n (transient), only pa[4][2]
//       (16 regs) of P fragments live; 8 independent MFMA per V pair.
//   (2) launch_bounds(256) (256-reg budget): ~50 arch + 64 acc fits.
// Block: 256 thr = 4 waves; (head, 16 q); wave owns k-quarter. Grid 1024.
// XCD swizzle: 2 heads/XCD -> K/V L2-resident.
// ---------------------------------------------------------------------------
__global__ __launch_bounds__(256)
void attn_k(const _Float16* __restrict__ Qg, const _Float16* __restrict__ Kg,
            const _Float16* __restrict__ Vg, const float* __restrict__ pm,
            const float* __restrict__ iwp, _Float16* __restrict__ comb)
{
    const int wg  = blockIdx.x;
    const int xcd = wg & 7;
    const int idx = wg >> 3;            // 0..127
    const int h   = xcd * 2 + (idx >> 6);
    const int qt  = idx & 63;           // 16-row q tile

    const int t = threadIdx.x;
    const int lane = t & 63;
    const int w = t >> 6;               // wave id = k-quarter
    const int lr = lane & 15;
    const int lg = lane >> 4;

    __shared__ union {
        _Float16 Ps[4][4][16][68];                       // [wave][moment][q][k64]
        struct { float Mom[4][16][4]; float Red[4][16][68]; } E;
    } U;
    __shared__ float sa[16], siw[16];
    __shared__ float gt[16][4];          // gamma_i^m / m!
    __shared__ float Ctab[16][4];        // c_m per q row

    if (t < 16) {
        float m = cosf(pm[t * NH + h]);
        sa[t] = m * m * 0.125f * 1.44269504f;   // a_i (log2 scale, on raw dot)
        siw[t] = iwp[t];
    }
    __syncthreads();

    float amin = sa[0], amax = sa[0];
#pragma unroll
    for (int i = 1; i < NWL; ++i) {
        amin = fminf(amin, sa[i]);
        amax = fmaxf(amax, sa[i]);
    }
    const float abar = 0.5f * (amin + amax);

    if (t < 16) {
        float g = (sa[t] - abar) * 0.69314718f;  // natural-log residual
        gt[t][0] = 1.f;
        gt[t][1] = g;
        gt[t][2] = g * g * 0.5f;
        gt[t][3] = g * g * g * (1.f / 6.f);
    }
    // gt is read only after the post-k-loop barrier -> ordering safe

    // Q fragments (B-operand): col = q-local = lr, k-seg = lg*8
    const _Float16* Qrow = Qg + ((size_t)h << 16) + (size_t)(qt * 16 + lr) * 64;
    half8 q0 = *(const half8*)&Qrow[lg * 8];
    half8 q1 = *(const half8*)&Qrow[32 + lg * 8];

    const _Float16* Kq = Kg + ((size_t)h << 16) + (size_t)(w * 256) * 64;  // k-quarter
    const _Float16* Vh = Vg + ((size_t)h << 16);                           // V^T [d][s]

    float M0 = 0.f, M1 = 0.f, M2 = 0.f, M3 = 0.f;
    f32x4 macc[4][4];
#pragma unroll
    for (int m = 0; m < 4; ++m)
#pragma unroll
        for (int n = 0; n < 4; ++n) macc[m][n] = (f32x4){0.f, 0.f, 0.f, 0.f};

    for (int ch = 0; ch < 4; ++ch) {
        // ---- QK^T + moment powers for this 64k chunk ----
#pragma unroll
        for (int kf = 0; kf < 4; ++kf) {
            const _Float16* Kr = Kq + (size_t)(ch * 64 + kf * 16 + lr) * 64;
            half8 a0 = *(const half8*)&Kr[lg * 8];
            half8 a1 = *(const half8*)&Kr[32 + lg * 8];
            f32x4 s2 = (f32x4){0.f, 0.f, 0.f, 0.f};
            s2 = __builtin_amdgcn_mfma_f32_16x16x32_f16(a0, q0, s2, 0, 0, 0);
            s2 = __builtin_amdgcn_mfma_f32_16x16x32_f16(a1, q1, s2, 0, 0, 0);
            half4 p0, p1, p2, p3;
#pragma unroll
            for (int r = 0; r < 4; ++r) {
                const float sv = s2[r];
                const float e   = exp2f(abar * sv);
                const float es  = e * sv;
                const float tt  = sv * sv;
                const float et  = e * tt;
                const float est = es * tt;
                M0 += e; M1 += es; M2 += et; M3 += est;
                p0[r] = (_Float16)e;
                p1[r] = (_Float16)es;
                p2[r] = (_Float16)et;
                p3[r] = (_Float16)est;
            }
            const int kl = kf * 16 + lg * 4;   // P_m[q=lr][k-local], wave-private
            *(half4*)&U.Ps[w][0][lr][kl] = p0;
            *(half4*)&U.Ps[w][1][lr][kl] = p1;
            *(half4*)&U.Ps[w][2][lr][kl] = p2;
            *(half4*)&U.Ps[w][3][lr][kl] = p3;
        }
        // ---- read the 4 moment-P fragments ONCE (16 regs live) ----
        half8 pa[4][2];
#pragma unroll
        for (int m = 0; m < 4; ++m) {
            pa[m][0] = *(const half8*)&U.Ps[w][m][lr][lg * 8];
            pa[m][1] = *(const half8*)&U.Ps[w][m][lr][32 + lg * 8];
        }
        // ---- PV: n OUTER so each V pair is loaded once and feeds 8 MFMA ----
        const int kcol = w * 256 + ch * 64;
#pragma unroll
        for (int n = 0; n < 4; ++n) {
            const _Float16* Vr = Vh + (size_t)(n * 16 + lr) * 1024 + kcol;
            half8 vb0 = *(const half8*)&Vr[lg * 8];
            half8 vb1 = *(const half8*)&Vr[32 + lg * 8];
#pragma unroll
            for (int m = 0; m < 4; ++m) {
                macc[m][n] = __builtin_amdgcn_mfma_f32_16x16x32_f16(pa[m][0], vb0, macc[m][n], 0, 0, 0);
                macc[m][n] = __builtin_amdgcn_mfma_f32_16x16x32_f16(pa[m][1], vb1, macc[m][n], 0, 0, 0);
            }
        }
    }
    __syncthreads();   // all waves done with Ps; union region switches to E

    // ---- scalar moment reduce: lanes with same lr sum over lg (k bits) ----
#pragma unroll
    for (int off = 16; off < 64; off <<= 1) {
        M0 += __shfl_xor(M0, off);
        M1 += __shfl_xor(M1, off);
        M2 += __shfl_xor(M2, off);
        M3 += __shfl_xor(M3, off);
    }
    if (lg == 0) {
        U.E.Mom[w][lr][0] = M0;
        U.E.Mom[w][lr][1] = M1;
        U.E.Mom[w][lr][2] = M2;
        U.E.Mom[w][lr][3] = M3;
    }
    __syncthreads();

    float Mf[4];
#pragma unroll
    for (int m = 0; m < 4; ++m)
        Mf[m] = U.E.Mom[0][lr][m] + U.E.Mom[1][lr][m] + U.E.Mom[2][lr][m] + U.E.Mom[3][lr][m];

    // den_i = sum_m gt[i][m] Mf[m]; wgt = iw/(16 den); c_m = sum_i wgt gt[i][m]
    float c0 = 0.f, c1 = 0.f, c2 = 0.f, c3 = 0.f;
#pragma unroll
    for (int i = 0; i < NWL; ++i) {
        float den = gt[i][0] * Mf[0];
        den = fmaf(gt[i][1], Mf[1], den);
        den = fmaf(gt[i][2], Mf[2], den);
        den = fmaf(gt[i][3], Mf[3], den);
        const float wgt = siw[i] / (den * 16.0f);
        c0 = fmaf(wgt, gt[i][0], c0);
        c1 = fmaf(wgt, gt[i][1], c1);
        c2 = fmaf(wgt, gt[i][2], c2);
        c3 = fmaf(wgt, gt[i][3], c3);
    }
    if (t < 16) {   // t<16 <=> (w==0, lg==0, lr==t): canonical writer per q row
        Ctab[t][0] = c0; Ctab[t][1] = c1; Ctab[t][2] = c2; Ctab[t][3] = c3;
    }
    __syncthreads();

    // ---- combine 4 moment accumulators; write per-wave O partials ----
    // macc C-layout: row q = lg*4 + r, col d = n*16 + lr
#pragma unroll
    for (int n = 0; n < 4; ++n) {
#pragma unroll
        for (int r = 0; r < 4; ++r) {
            const int q = lg * 4 + r;
            float o = Ctab[q][0] * macc[0][n][r];
            o = fmaf(Ctab[q][1], macc[1][n][r], o);
            o = fmaf(Ctab[q][2], macc[2][n][r], o);
            o = fmaf(Ctab[q][3], macc[3][n][r], o);
            U.E.Red[w][q][n * 16 + lr] = o;
        }
    }
    __syncthreads();

    // ---- final cross-wave reduce: thread t -> q = t>>4, d0 = (t&15)*4 ----
    {
        const int q = t >> 4;
        const int d0 = (t & 15) * 4;
        f32x4 s0 = *(const f32x4*)&U.E.Red[0][q][d0];
        f32x4 s1 = *(const f32x4*)&U.E.Red[1][q][d0];
        f32x4 s2v = *(const f32x4*)&U.E.Red[2][q][d0];
        f32x4 s3 = *(const f32x4*)&U.E.Red[3][q][d0];
        f32x4 sum = s0 + s1 + s2v + s3;
        half4 o;
#pragma unroll
        for (int r = 0; r < 4; ++r) o[r] = (_Float16)sum[r];
        *(half4*)&comb[(size_t)(qt * 16 + q) * 1024 + h * 64 + d0] = o;
    }
}

// ---------------------------------------------------------------------------
extern "C" void kernel_launch(void* const* d_in, const int* in_sizes, int n_in,
                              void* d_out, int out_size, void* d_ws, size_t ws_size,
                              hipStream_t stream)
{
    const float* x  = (const float*)d_in[0];
    const float* Wq = (const float*)d_in[1];
    const float* bq = (const float*)d_in[2];
    const float* Wk = (const float*)d_in[3];
    const float* bk = (const float*)d_in[4];
    const float* Wv = (const float*)d_in[5];
    const float* bv = (const float*)d_in[6];
    const float* Wo = (const float*)d_in[7];
    const float* bo = (const float*)d_in[8];
    const float* pm = (const float*)d_in[9];
    const float* iw = (const float*)d_in[10];
    float* out = (float*)d_out;

    // ws (f16 elems): Xh 1M (reused as comb) | WT 4M | Q 1M | K 1M | Vt 1M = 16 MB
    _Float16* Xh = (_Float16*)d_ws;
    _Float16* WT = Xh + (1u << 20);
    _Float16* Qh = WT + (4u << 20);
    _Float16* Kh = Qh + (1u << 20);
    _Float16* Vt = Kh + (1u << 20);
    _Float16* comb = Xh;   // Xh dead after QKV GEMM

    dim3 blk(256);
    cast_x_k<<<dim3(512), blk, 0, stream>>>(x, Xh);
    castT_w<<<dim3(16, 16, 4), blk, 0, stream>>>(Wq, Wk, Wv, Wo, WT);
    gemm_mfma<1><<<dim3(16, 16, 3), blk, 0, stream>>>(Xh, WT, bq, bk, bv, Qh, Kh, Vt);
    attn_k<<<dim3(1024), blk, 0, stream>>>(Qh, Kh, Vt, pm, iw, comb);
    gemm_mfma<0><<<dim3(16, 16, 1), blk, 0, stream>>>(
        comb, WT + (3u << 20), bo, bo, bo, out, out, out);
}